// Round 24
// baseline (31.604 us; speedup 1.0000x reference)
//
#include <hip/hip_runtime.h>

#define NTYPES 216
#define NPIX   4096
#define KD     576      // C*3*3
#define ROWLEN 577      // KD + bias
#define NPC    32       // pixels per GEMM chunk
#define PSTR   640      // u16 elements per LDS row (576 data + 64 shift pad)
#define MAXB   160      // max supported bucket size (mean 19)

typedef __attribute__((ext_vector_type(8))) short short8;
typedef __attribute__((ext_vector_type(4))) float f32x4;
typedef __attribute__((ext_vector_type(4), aligned(4))) float f32x4u;  // 4B-aligned
typedef __attribute__((ext_vector_type(8))) unsigned short u16x8;
typedef __attribute__((ext_vector_type(4))) unsigned short u16x4;
typedef __attribute__((ext_vector_type(2))) unsigned short u16x2;

static __device__ __forceinline__ unsigned short f2bf(float f) {
    unsigned u = __builtin_bit_cast(unsigned, f);
    unsigned r = (u + 0x7FFFu + ((u >> 16) & 1u)) >> 16;  // RNE
    return (unsigned short)r;
}

// ---------- Kernel A: 256 blocks, grouped conv (CHW compute, HWC store) ----------
__global__ __launch_bounds__(256) void prep_kernel(
        const float* __restrict__ x, const float* __restrict__ w1,
        const float* __restrict__ b1, unsigned short* __restrict__ hbf) {
    int tid = threadIdx.x;
    int flat = blockIdx.x * 256 + tid;   // c(6) | y(6) | x4(4)
    int x4 = flat & 15;
    int y  = (flat >> 4) & 63;
    int c  = flat >> 10;                  // block-uniform
    int g  = c >> 4;
    const float* wrow = w1 + c * 144;
    float o0, o1, o2, o3;
    o0 = o1 = o2 = o3 = b1[c];
    #pragma unroll
    for (int ci = 0; ci < 16; ++ci) {
        const float* xp = x + (g * 16 + ci) * 4096;
        #pragma unroll
        for (int dy = 0; dy < 3; ++dy) {
            int yy = y + dy - 1;
            if (yy < 0 || yy > 63) continue;
            const float* row = xp + yy * 64 + x4 * 4;
            f32x4 mm = *(const f32x4*)row;
            float xl = (x4 > 0)  ? row[-1] : 0.f;
            float xr = (x4 < 15) ? row[4]  : 0.f;
            float wa = wrow[ci * 9 + dy * 3 + 0];
            float wb = wrow[ci * 9 + dy * 3 + 1];
            float wc = wrow[ci * 9 + dy * 3 + 2];
            o0 = fmaf(wa, xl,    fmaf(wb, mm[0], fmaf(wc, mm[1], o0)));
            o1 = fmaf(wa, mm[0], fmaf(wb, mm[1], fmaf(wc, mm[2], o1)));
            o2 = fmaf(wa, mm[1], fmaf(wb, mm[2], fmaf(wc, mm[3], o2)));
            o3 = fmaf(wa, mm[2], fmaf(wb, mm[3], fmaf(wc, xr,    o3)));
        }
    }
    int pix0 = y * 64 + x4 * 4;
    hbf[(pix0 + 0) * 64 + c] = f2bf(fmaxf(o0, 0.f));
    hbf[(pix0 + 1) * 64 + c] = f2bf(fmaxf(o1, 0.f));
    hbf[(pix0 + 2) * 64 + c] = f2bf(fmaxf(o2, 0.f));
    hbf[(pix0 + 3) * 64 + c] = f2bf(fmaxf(o3, 0.f));
}

// ---------- Kernel B: 216 blocks x 1024; issue-early/write-late W-stream ----------
__global__ __launch_bounds__(1024) void dyn_kernel(
        const unsigned short* __restrict__ hbf, const float* __restrict__ emb,
        const float* __restrict__ w2, const float* __restrict__ b2,
        const float* __restrict__ x, const int* __restrict__ buckets,
        float* __restrict__ out) {

    __shared__ alignas(16) unsigned short Wl[64 * PSTR];   // 80 KB  filter tile (bf16, native k)
    __shared__ alignas(16) unsigned short Pl[NPC * PSTR];  // 40 KB  patches (bf16, native k)
    __shared__ alignas(16) unsigned short Dl[NPC * 72];    //  4.5 KB intermediate
    __shared__ alignas(16) unsigned short w2l[64 * 72];    //  9 KB  1x1 weights bf16
    __shared__ float bias_l[64];
    __shared__ int pixs[MAXB];
    __shared__ int cnt_l;

    int b   = blockIdx.x;
    int tid = threadIdx.x;

    const float* eb = emb + (size_t)b * 36928;

    // ---- ISSUE ALL W GLOBAL LOADS FIRST (registers; nothing depends on LDS/scan) ----
    int wr[5], wc0[5];
    f32x4u wA[5], wB[5];
    #pragma unroll
    for (int it = 0; it < 4; ++it) {
        int u  = tid + it * 1024;
        int r  = u / 72;
        int c0 = (u - r * 72) * 8;
        wr[it] = r; wc0[it] = c0;
        const float* src = eb + r * ROWLEN + c0;
        wA[it] = *(const f32x4u*)src;
        wB[it] = *(const f32x4u*)(src + 4);
    }
    bool has5 = (tid < 512);
    if (has5) {
        int u  = tid + 4096;
        int r  = u / 72;
        int c0 = (u - r * 72) * 8;
        wr[4] = r; wc0[4] = c0;
        const float* src = eb + r * ROWLEN + c0;
        wA[4] = *(const f32x4u*)src;
        wB[4] = *(const f32x4u*)(src + 4);
    }
    float biasv = (tid < 64) ? eb[tid * ROWLEN + KD] : 0.f;
    f32x4 w2a = {0,0,0,0}, w2b = {0,0,0,0};
    if (tid < 512) {
        const float* src = w2 + (tid >> 3) * 64 + (tid & 7) * 8;
        w2a = *(const f32x4*)src;
        w2b = *(const f32x4*)(src + 4);
    }

    // ---- scan buckets under the W-load latency (LDS/atomic pipe) ----
    if (tid == 0) cnt_l = 0;
    __syncthreads();
    {
        int i0 = tid * 4;   // 1024 threads x 4 = 4096
        int4 v = *(const int4*)&buckets[i0];
        if (v.x == b) { int p = atomicAdd(&cnt_l, 1); if (p < MAXB) pixs[p] = i0 + 0; }
        if (v.y == b) { int p = atomicAdd(&cnt_l, 1); if (p < MAXB) pixs[p] = i0 + 1; }
        if (v.z == b) { int p = atomicAdd(&cnt_l, 1); if (p < MAXB) pixs[p] = i0 + 2; }
        if (v.w == b) { int p = atomicAdd(&cnt_l, 1); if (p < MAXB) pixs[p] = i0 + 3; }
    }
    __syncthreads();
    int n = cnt_l < MAXB ? cnt_l : MAXB;
    if (n <= 0) return;

    // gather roles: 32 threads per pixel slot, u16x2 (2 channels) each
    int gp = tid >> 5;          // pixel slot 0..31
    int gk = tid & 31;          // channel pair index (cch = 2*gk, 2*gk+1)
    unsigned short* pdst = Pl + gp * PSTR + (gp & 7) * 8;

    // ---- P0 gather into registers (overlaps W-load tail) ----
    int pixel0 = (gp < n) ? pixs[gp] : -1;
    u16x2 p0[9];
    {
        int py = pixel0 >> 6, px = pixel0 & 63;
        #pragma unroll
        for (int dy = 0; dy < 3; ++dy) {
            int yy = py + dy - 1;
            bool yok = (yy >= 0 && yy < 64);
            #pragma unroll
            for (int dx = 0; dx < 3; ++dx) {
                int pos = dy * 3 + dx;
                int xx = px + dx - 1;
                u16x2 v = {0, 0};
                if (pixel0 >= 0 && yok && xx >= 0 && xx < 64)
                    v = *(const u16x2*)&hbf[(yy * 64 + xx) * 64 + gk * 2];
                p0[pos] = v;
            }
        }
    }

    // ---- WRITE-LATE: convert + store W / w2 / bias / P0 to LDS ----
    #pragma unroll
    for (int it = 0; it < 5; ++it) {
        if (it < 4 || has5) {
            unsigned pk0, pk1, pk2, pk3;
            asm("v_cvt_pk_bf16_f32 %0, %1, %2" : "=v"(pk0) : "v"(wA[it][0]), "v"(wA[it][1]));
            asm("v_cvt_pk_bf16_f32 %0, %1, %2" : "=v"(pk1) : "v"(wA[it][2]), "v"(wA[it][3]));
            asm("v_cvt_pk_bf16_f32 %0, %1, %2" : "=v"(pk2) : "v"(wB[it][0]), "v"(wB[it][1]));
            asm("v_cvt_pk_bf16_f32 %0, %1, %2" : "=v"(pk3) : "v"(wB[it][2]), "v"(wB[it][3]));
            u16x8 v;
            v[0] = (unsigned short)(pk0 & 0xFFFFu); v[1] = (unsigned short)(pk0 >> 16);
            v[2] = (unsigned short)(pk1 & 0xFFFFu); v[3] = (unsigned short)(pk1 >> 16);
            v[4] = (unsigned short)(pk2 & 0xFFFFu); v[5] = (unsigned short)(pk2 >> 16);
            v[6] = (unsigned short)(pk3 & 0xFFFFu); v[7] = (unsigned short)(pk3 >> 16);
            *(u16x8*)&Wl[wr[it] * PSTR + (wr[it] & 7) * 8 + wc0[it]] = v;
        }
    }
    if (tid < 64) bias_l[tid] = biasv;
    if (tid < 512) {
        u16x8 v;
        #pragma unroll
        for (int j = 0; j < 4; ++j) { v[j] = f2bf(w2a[j]); v[j + 4] = f2bf(w2b[j]); }
        *(u16x8*)&w2l[(tid >> 3) * 72 + (tid & 7) * 8] = v;
    }
    {
        int cA = (2 * gk) * 9, cB = (2 * gk + 1) * 9;
        #pragma unroll
        for (int pos = 0; pos < 9; ++pos) {
            pdst[cA + pos] = p0[pos][0];
            pdst[cB + pos] = p0[pos][1];
        }
    }

    __syncthreads();   // W / P0 / w2 / bias all ready

    int lane = tid & 63;
    int wv   = tid >> 6;        // 0..15; waves 0..7 compute
    int m    = wv & 3;
    int ph   = (wv >> 2) & 1;
    int ra   = lane & 15;
    int kg   = lane >> 4;

    int rowW = m * 16 + ra;
    const unsigned short* pA = Wl + rowW * PSTR + (rowW & 7) * 8 + kg * 8;
    int ob0 = m * 16 + kg * 4;
    float bias0 = bias_l[ob0 + 0], bias1 = bias_l[ob0 + 1];
    float bias2 = bias_l[ob0 + 2], bias3 = bias_l[ob0 + 3];
    const unsigned short* pB = Pl + (ph * 16 + ra) * PSTR + (ra & 7) * 8 + kg * 8;

    for (int base = 0; base < n; base += NPC) {
        if (base > 0) {
            // rare tail: gather directly to Pl (all 1024 threads), native-k scatter
            int pixel = (base + gp < n) ? pixs[base + gp] : -1;
            int py = pixel >> 6, px = pixel & 63;
            int cA = (2 * gk) * 9, cB = (2 * gk + 1) * 9;
            #pragma unroll
            for (int dy = 0; dy < 3; ++dy) {
                int yy = py + dy - 1;
                bool yok = (yy >= 0 && yy < 64);
                #pragma unroll
                for (int dx = 0; dx < 3; ++dx) {
                    int pos = dy * 3 + dx;
                    int xx = px + dx - 1;
                    u16x2 v = {0, 0};
                    if (pixel >= 0 && yok && xx >= 0 && xx < 64)
                        v = *(const u16x2*)&hbf[(yy * 64 + xx) * 64 + gk * 2];
                    pdst[cA + pos] = v[0];
                    pdst[cB + pos] = v[1];
                }
            }
            __syncthreads();   // P ready (also separates Dl overwrite from prev reads)
        }

        if (wv < 8) {
            // ---- K-loop: 18 A-reads + 18 B-reads from LDS + 18 MFMA ----
            f32x4 acc = {0.f, 0.f, 0.f, 0.f};
            #pragma unroll
            for (int ck = 0; ck < 9; ++ck) {
                #pragma unroll
                for (int ks = 0; ks < 2; ++ks) {
                    u16x8 av = *(const u16x8*)(pA + ck * 64 + ks * 32);
                    u16x8 bv = *(const u16x8*)(pB + ck * 64 + ks * 32);
                    acc = __builtin_amdgcn_mfma_f32_16x16x32_bf16(
                              __builtin_bit_cast(short8, av),
                              __builtin_bit_cast(short8, bv), acc, 0, 0, 0);
                }
            }
            // ---- bias + relu -> Dl (bf16) ----
            int pi = ph * 16 + ra;
            u16x4 dv;
            dv[0] = f2bf(fmaxf(acc[0] + bias0, 0.f));
            dv[1] = f2bf(fmaxf(acc[1] + bias1, 0.f));
            dv[2] = f2bf(fmaxf(acc[2] + bias2, 0.f));
            dv[3] = f2bf(fmaxf(acc[3] + bias3, 0.f));
            *(u16x4*)&Dl[pi * 72 + ob0] = dv;
        }
        __syncthreads();   // D ready (all Pl reads for this chunk done)

        if (wv < 8) {
            // ---- GEMM2: 1x1 conv (K=64) ----
            f32x4 acc2 = {0.f, 0.f, 0.f, 0.f};
            #pragma unroll
            for (int ks = 0; ks < 2; ++ks) {
                u16x8 a2  = *(const u16x8*)&w2l[(m * 16 + ra) * 72 + ks * 32 + kg * 8];
                u16x8 b2v = *(const u16x8*)&Dl[(ph * 16 + ra) * 72 + ks * 32 + kg * 8];
                acc2 = __builtin_amdgcn_mfma_f32_16x16x32_bf16(
                           __builtin_bit_cast(short8, a2),
                           __builtin_bit_cast(short8, b2v), acc2, 0, 0, 0);
            }
            // ---- epilogue: + b2 + residual, relu, store ----
            int pi = ph * 16 + ra;
            int pixel = (base + pi < n) ? pixs[base + pi] : -1;
            if (pixel >= 0) {
                #pragma unroll
                for (int j = 0; j < 4; ++j) {
                    int o = ob0 + j;
                    float v = acc2[j] + b2[o] + x[o * 4096 + pixel];
                    out[o * 4096 + pixel] = fmaxf(v, 0.f);
                }
            }
        }
    }
}

extern "C" void kernel_launch(void* const* d_in, const int* in_sizes, int n_in,
                              void* d_out, int out_size, void* d_ws, size_t ws_size,
                              hipStream_t stream) {
    const float* x       = (const float*)d_in[0];
    const int*   buckets = (const int*)d_in[1];
    const float* w1      = (const float*)d_in[2];
    const float* b1      = (const float*)d_in[3];
    const float* emb     = (const float*)d_in[4];
    const float* w2      = (const float*)d_in[5];
    const float* b2      = (const float*)d_in[6];
    float* out = (float*)d_out;

    unsigned short* hbf = (unsigned short*)d_ws;            // 512 KB (HWC)

    prep_kernel<<<256, 256, 0, stream>>>(x, w1, b1, hbf);
    dyn_kernel<<<NTYPES, 1024, 0, stream>>>(hbf, emb, w2, b2, x, buckets, out);
}

// Round 25
// 30.170 us; speedup vs baseline: 1.0476x; 1.0476x over previous
//
#include <hip/hip_runtime.h>

#define NTYPES 216
#define NPIX   4096
#define KD     576      // C*3*3
#define ROWLEN 577      // KD + bias
#define NPC    32       // pixels per GEMM chunk
#define PSTR   640      // u16 elements per LDS row (576 data + 64 shift pad)
#define MAXB   160      // max supported bucket size (mean 19)

typedef __attribute__((ext_vector_type(8))) short short8;
typedef __attribute__((ext_vector_type(2))) float f32x2;
typedef __attribute__((ext_vector_type(4))) float f32x4;
typedef __attribute__((ext_vector_type(4), aligned(4))) float f32x4u;  // 4B-aligned
typedef __attribute__((ext_vector_type(8))) unsigned short u16x8;
typedef __attribute__((ext_vector_type(4))) unsigned short u16x4;
typedef __attribute__((ext_vector_type(2))) unsigned short u16x2;

static __device__ __forceinline__ unsigned short f2bf(float f) {
    unsigned u = __builtin_bit_cast(unsigned, f);
    unsigned r = (u + 0x7FFFu + ((u >> 16) & 1u)) >> 16;  // RNE
    return (unsigned short)r;
}

// ---------- Kernel A: 512 blocks x 256, 2 px/thread, c wave-uniform (s_load w1) ----------
__global__ __launch_bounds__(256) void prep_kernel(
        const float* __restrict__ x, const float* __restrict__ w1,
        const float* __restrict__ b1, unsigned short* __restrict__ hbf) {
    int tid = threadIdx.x;
    int c   = blockIdx.x >> 3;                    // uniform per block -> SGPR
    int p2  = ((blockIdx.x & 7) << 8) + tid;      // pixel-pair 0..2047
    int y   = p2 >> 5;
    int x2  = (p2 & 31) * 2;
    int g   = c >> 4;
    const float* wrow = w1 + c * 144;             // uniform base -> s_loads
    float o0 = b1[c], o1 = o0;
    #pragma unroll
    for (int ci = 0; ci < 16; ++ci) {
        const float* xp = x + (g * 16 + ci) * 4096;
        #pragma unroll
        for (int dy = 0; dy < 3; ++dy) {
            int yy = y + dy - 1;
            if (yy < 0 || yy > 63) continue;
            const float* row = xp + yy * 64 + x2;
            f32x2 m = *(const f32x2*)row;
            float xl = (x2 > 0)  ? row[-1] : 0.f;
            float xr = (x2 < 62) ? row[2]  : 0.f;
            float wa = wrow[ci * 9 + dy * 3 + 0];
            float wb = wrow[ci * 9 + dy * 3 + 1];
            float wc = wrow[ci * 9 + dy * 3 + 2];
            o0 = fmaf(wa, xl,   fmaf(wb, m[0], fmaf(wc, m[1], o0)));
            o1 = fmaf(wa, m[0], fmaf(wb, m[1], fmaf(wc, xr,   o1)));
        }
    }
    int pix = y * 64 + x2;
    hbf[(pix + 0) * 64 + c] = f2bf(fmaxf(o0, 0.f));
    hbf[(pix + 1) * 64 + c] = f2bf(fmaxf(o1, 0.f));
}

// ---------- Kernel B: 216 blocks x 1024; native-k order (W contiguous, P scatter) ----------
__global__ __launch_bounds__(1024) void dyn_kernel(
        const unsigned short* __restrict__ hbf, const float* __restrict__ emb,
        const float* __restrict__ w2, const float* __restrict__ b2,
        const float* __restrict__ x, const int* __restrict__ buckets,
        float* __restrict__ out) {

    __shared__ alignas(16) unsigned short Wl[64 * PSTR];   // 80 KB  filter tile (bf16, native k)
    __shared__ alignas(16) unsigned short Pl[NPC * PSTR];  // 40 KB  patches (bf16, native k)
    __shared__ alignas(16) unsigned short Dl[NPC * 72];    //  4.5 KB intermediate
    __shared__ alignas(16) unsigned short w2l[64 * 72];    //  9 KB  1x1 weights bf16
    __shared__ float bias_l[64];
    __shared__ int pixs[MAXB];
    __shared__ int cnt_l;

    int b   = blockIdx.x;
    int tid = threadIdx.x;

    // ---- phase 0: self-scan buckets (one int4 per thread) ----
    if (tid == 0) cnt_l = 0;
    __syncthreads();
    {
        int i0 = tid * 4;   // 1024 threads x 4 = 4096
        int4 v = *(const int4*)&buckets[i0];
        if (v.x == b) { int p = atomicAdd(&cnt_l, 1); if (p < MAXB) pixs[p] = i0 + 0; }
        if (v.y == b) { int p = atomicAdd(&cnt_l, 1); if (p < MAXB) pixs[p] = i0 + 1; }
        if (v.z == b) { int p = atomicAdd(&cnt_l, 1); if (p < MAXB) pixs[p] = i0 + 2; }
        if (v.w == b) { int p = atomicAdd(&cnt_l, 1); if (p < MAXB) pixs[p] = i0 + 3; }
    }
    __syncthreads();
    int n = cnt_l < MAXB ? cnt_l : MAXB;
    if (n <= 0) return;

    const float* eb = emb + (size_t)b * 36928;

    // ---- small stages first: their loads issue into the latency shadow ----
    if (tid < 64) bias_l[tid] = eb[tid * ROWLEN + KD];
    if (tid < 512) {
        int o = tid >> 3, i8 = (tid & 7) * 8;
        const float* src = w2 + o * 64 + i8;
        u16x8 v;
        #pragma unroll
        for (int j = 0; j < 8; ++j) v[j] = f2bf(src[j]);
        *(u16x8*)&w2l[o * 72 + i8] = v;
    }

    // gather roles: 32 threads per pixel slot, u16x2 (2 channels) each
    int gp = tid >> 5;          // pixel slot 0..31
    int gk = tid & 31;          // channel pair index (cch = 2*gk, 2*gk+1)
    unsigned short* pdst = Pl + gp * PSTR + (gp & 7) * 8;

    // ---- P0 gather into registers (issued early; rides under the W-stream) ----
    int pixel0 = (gp < n) ? pixs[gp] : -1;
    u16x2 p0[9];
    {
        int py = pixel0 >> 6, px = pixel0 & 63;
        #pragma unroll
        for (int dy = 0; dy < 3; ++dy) {
            int yy = py + dy - 1;
            bool yok = (yy >= 0 && yy < 64);
            #pragma unroll
            for (int dx = 0; dx < 3; ++dx) {
                int pos = dy * 3 + dx;
                int xx = px + dx - 1;
                u16x2 v = {0, 0};
                if (pixel0 >= 0 && yok && xx >= 0 && xx < 64)
                    v = *(const u16x2*)&hbf[(yy * 64 + xx) * 64 + gk * 2];
                p0[pos] = v;
            }
        }
    }

    // ---- W-stream: coalesced f32x4 loads; cvt_pk; CONTIGUOUS u16x8 LDS writes ----
    #pragma unroll
    for (int it = 0; it < 5; ++it) {
        int u = tid + it * 1024;
        if (u < 4608) {
            int r  = u / 72;
            int c0 = (u - r * 72) * 8;
            const float* src = eb + r * ROWLEN + c0;
            f32x4u a  = *(const f32x4u*)src;
            f32x4u bb = *(const f32x4u*)(src + 4);
            unsigned pk0, pk1, pk2, pk3;
            asm("v_cvt_pk_bf16_f32 %0, %1, %2" : "=v"(pk0) : "v"(a[0]),  "v"(a[1]));
            asm("v_cvt_pk_bf16_f32 %0, %1, %2" : "=v"(pk1) : "v"(a[2]),  "v"(a[3]));
            asm("v_cvt_pk_bf16_f32 %0, %1, %2" : "=v"(pk2) : "v"(bb[0]), "v"(bb[1]));
            asm("v_cvt_pk_bf16_f32 %0, %1, %2" : "=v"(pk3) : "v"(bb[2]), "v"(bb[3]));
            u16x8 v;
            v[0] = (unsigned short)(pk0 & 0xFFFFu); v[1] = (unsigned short)(pk0 >> 16);
            v[2] = (unsigned short)(pk1 & 0xFFFFu); v[3] = (unsigned short)(pk1 >> 16);
            v[4] = (unsigned short)(pk2 & 0xFFFFu); v[5] = (unsigned short)(pk2 >> 16);
            v[6] = (unsigned short)(pk3 & 0xFFFFu); v[7] = (unsigned short)(pk3 >> 16);
            *(u16x8*)&Wl[r * PSTR + (r & 7) * 8 + c0] = v;
        }
    }

    // ---- write P0 regs to Pl: native-k scatter (c = cch*9 + pos), 18 b16 writes ----
    {
        int cA = (2 * gk) * 9, cB = (2 * gk + 1) * 9;
        #pragma unroll
        for (int pos = 0; pos < 9; ++pos) {
            pdst[cA + pos] = p0[pos][0];
            pdst[cB + pos] = p0[pos][1];
        }
    }

    __syncthreads();   // W / P0 / w2 / bias all ready

    int lane = tid & 63;
    int wv   = tid >> 6;        // 0..15; waves 0..7 compute
    int m    = wv & 3;
    int ph   = (wv >> 2) & 1;
    int ra   = lane & 15;
    int kg   = lane >> 4;

    int rowW = m * 16 + ra;
    const unsigned short* pA = Wl + rowW * PSTR + (rowW & 7) * 8 + kg * 8;
    int ob0 = m * 16 + kg * 4;
    float bias0 = bias_l[ob0 + 0], bias1 = bias_l[ob0 + 1];
    float bias2 = bias_l[ob0 + 2], bias3 = bias_l[ob0 + 3];
    const unsigned short* pB = Pl + (ph * 16 + ra) * PSTR + (ra & 7) * 8 + kg * 8;

    for (int base = 0; base < n; base += NPC) {
        if (base > 0) {
            // rare tail: gather directly to Pl (all 1024 threads), native-k scatter
            int pixel = (base + gp < n) ? pixs[base + gp] : -1;
            int py = pixel >> 6, px = pixel & 63;
            int cA = (2 * gk) * 9, cB = (2 * gk + 1) * 9;
            #pragma unroll
            for (int dy = 0; dy < 3; ++dy) {
                int yy = py + dy - 1;
                bool yok = (yy >= 0 && yy < 64);
                #pragma unroll
                for (int dx = 0; dx < 3; ++dx) {
                    int pos = dy * 3 + dx;
                    int xx = px + dx - 1;
                    u16x2 v = {0, 0};
                    if (pixel >= 0 && yok && xx >= 0 && xx < 64)
                        v = *(const u16x2*)&hbf[(yy * 64 + xx) * 64 + gk * 2];
                    pdst[cA + pos] = v[0];
                    pdst[cB + pos] = v[1];
                }
            }
            __syncthreads();   // P ready (also separates Dl overwrite from prev reads)
        }

        if (wv < 8) {
            // ---- K-loop: 18 A-reads + 18 B-reads from LDS + 18 MFMA ----
            f32x4 acc = {0.f, 0.f, 0.f, 0.f};
            #pragma unroll
            for (int ck = 0; ck < 9; ++ck) {
                #pragma unroll
                for (int ks = 0; ks < 2; ++ks) {
                    u16x8 av = *(const u16x8*)(pA + ck * 64 + ks * 32);
                    u16x8 bv = *(const u16x8*)(pB + ck * 64 + ks * 32);
                    acc = __builtin_amdgcn_mfma_f32_16x16x32_bf16(
                              __builtin_bit_cast(short8, av),
                              __builtin_bit_cast(short8, bv), acc, 0, 0, 0);
                }
            }
            // ---- bias + relu -> Dl (bf16) ----
            int pi = ph * 16 + ra;
            u16x4 dv;
            dv[0] = f2bf(fmaxf(acc[0] + bias0, 0.f));
            dv[1] = f2bf(fmaxf(acc[1] + bias1, 0.f));
            dv[2] = f2bf(fmaxf(acc[2] + bias2, 0.f));
            dv[3] = f2bf(fmaxf(acc[3] + bias3, 0.f));
            *(u16x4*)&Dl[pi * 72 + ob0] = dv;
        }
        __syncthreads();   // D ready (all Pl reads for this chunk done)

        if (wv < 8) {
            // ---- GEMM2: 1x1 conv (K=64) ----
            f32x4 acc2 = {0.f, 0.f, 0.f, 0.f};
            #pragma unroll
            for (int ks = 0; ks < 2; ++ks) {
                u16x8 a2  = *(const u16x8*)&w2l[(m * 16 + ra) * 72 + ks * 32 + kg * 8];
                u16x8 b2v = *(const u16x8*)&Dl[(ph * 16 + ra) * 72 + ks * 32 + kg * 8];
                acc2 = __builtin_amdgcn_mfma_f32_16x16x32_bf16(
                           __builtin_bit_cast(short8, a2),
                           __builtin_bit_cast(short8, b2v), acc2, 0, 0, 0);
            }
            // ---- epilogue: + b2 + residual, relu, store ----
            int pi = ph * 16 + ra;
            int pixel = (base + pi < n) ? pixs[base + pi] : -1;
            if (pixel >= 0) {
                #pragma unroll
                for (int j = 0; j < 4; ++j) {
                    int o = ob0 + j;
                    float v = acc2[j] + b2[o] + x[o * 4096 + pixel];
                    out[o * 4096 + pixel] = fmaxf(v, 0.f);
                }
            }
        }
    }
}

extern "C" void kernel_launch(void* const* d_in, const int* in_sizes, int n_in,
                              void* d_out, int out_size, void* d_ws, size_t ws_size,
                              hipStream_t stream) {
    const float* x       = (const float*)d_in[0];
    const int*   buckets = (const int*)d_in[1];
    const float* w1      = (const float*)d_in[2];
    const float* b1      = (const float*)d_in[3];
    const float* emb     = (const float*)d_in[4];
    const float* w2      = (const float*)d_in[5];
    const float* b2      = (const float*)d_in[6];
    float* out = (float*)d_out;

    unsigned short* hbf = (unsigned short*)d_ws;            // 512 KB (HWC)

    prep_kernel<<<512, 256, 0, stream>>>(x, w1, b1, hbf);
    dyn_kernel<<<NTYPES, 1024, 0, stream>>>(hbf, emb, w2, b2, x, buckets, out);
}